// Round 3
// baseline (1576.293 us; speedup 1.0000x reference)
//
#include <hip/hip_runtime.h>
#include <float.h>

// Problem constants (fixed by reference: B=8, D=64, H=64, W=64, K=8192)
constexpr int KCODES = 8192;
constexpr int DDIM   = 64;
constexpr int NTOK   = 32768;   // B*H*W
constexpr int MT     = 64;      // tokens per workgroup (one per lane)
constexpr int KPW    = KCODES / 4;  // codes per wave (4 waves split the codebook)

// ---- half-codebook-norm precompute: halfcn[k] = 0.5*||c_k||^2 (phase-1 only) ----
__global__ __launch_bounds__(256) void cnorm_kernel(
    const float* __restrict__ cb, float* __restrict__ halfcn) {
  int k = blockIdx.x * 256 + threadIdx.x;
  if (k >= KCODES) return;
  const float4* row = reinterpret_cast<const float4*>(cb + (size_t)k * DDIM);
  float s = 0.f;
#pragma unroll
  for (int q = 0; q < DDIM / 4; ++q) {
    float4 v = row[q];
    s += v.x * v.x + v.y * v.y + v.z * v.z + v.w * v.w;
  }
  halfcn[k] = 0.5f * s;
}

// Phase 1: fast fp32 candidate generation (top-2 per wave per token).
// Phase 2: numpy-fp32-faithful re-evaluation of candidates:
//   D(m,k) = fl32( fl32( S_m - 2*p ) + N_k ),  S/N via numpy pairwise-8 sums,
//   p = correctly-rounded fp32 of the fp64 dot. Tie -> lowest index
//   (np.argmin first-occurrence). This reproduces the reference's own
//   ulp(64)-level quantization of d2, which decides ~3 near-tie tokens.
__global__ __launch_bounds__(256, 2) void vq_kernel(
    const float* __restrict__ ze, const float* __restrict__ cb,
    const float* __restrict__ halfcn, float* __restrict__ out) {
  __shared__ float xlds[DDIM * MT];   // [d][m] stride 64
  __shared__ float rs1[4][MT];        // per-wave best fp32 score per token
  __shared__ int   ri1[4][MT];
  __shared__ float rs2[4][MT];        // per-wave 2nd-best
  __shared__ int   ri2[4][MT];
  __shared__ int   widx[MT];

  const int tid  = threadIdx.x;
  const int lane = tid & 63;          // token within tile
  const int wv   = tid >> 6;          // wave id 0..3
  const int t0   = blockIdx.x * MT;
  const int bb   = t0 >> 12;          // batch (tile never crosses batch: 4096%64==0)
  const int hw0  = t0 & 4095;
  const float* zbase = ze + (size_t)bb * (DDIM * 4096) + hw0;

  // ---- stage x tile: xlds[d*64 + m] = z_e[b, d, hw0+m] (coalesced rows) ----
#pragma unroll
  for (int p = 0; p < 16; ++p) {
    const int d = p * 4 + wv;
    xlds[d * MT + lane] = zbase[(size_t)d * 4096 + lane];
  }
  __syncthreads();

  // ---- own token's x row into registers ----
  float xr[DDIM];
#pragma unroll
  for (int d = 0; d < DDIM; ++d) xr[d] = xlds[d * MT + lane];

  // wave-uniform code-range base (scalarizable codebook loads)
  const int kb = __builtin_amdgcn_readfirstlane(wv) * KPW;

  float s1 = FLT_MAX, s2 = FLT_MAX;
  int   i1 = 0, i2 = 0;

  const float4* cb4 = reinterpret_cast<const float4*>(cb);

#pragma unroll 2
  for (int k = kb; k < kb + KPW; ++k) {
    const float4* crow = cb4 + (size_t)k * (DDIM / 4);
    float a0 = 0.f, a1 = 0.f, a2 = 0.f, a3 = 0.f;  // 4 chains for ILP
#pragma unroll
    for (int q = 0; q < DDIM / 4; ++q) {
      const float4 cv = crow[q];                   // wave-uniform address
      a0 += xr[4 * q + 0] * cv.x;
      a1 += xr[4 * q + 1] * cv.y;
      a2 += xr[4 * q + 2] * cv.z;
      a3 += xr[4 * q + 3] * cv.w;
    }
    const float s = halfcn[k] - ((a0 + a1) + (a2 + a3));
    if (s < s1)      { s2 = s1; i2 = i1; s1 = s; i1 = k; }
    else if (s < s2) { s2 = s;  i2 = k; }
  }

  rs1[wv][lane] = s1; ri1[wv][lane] = i1;
  rs2[wv][lane] = s2; ri2[wv][lane] = i2;
  __syncthreads();

  // ---- phase 2: numpy-faithful fp32 decision over the 8 candidates ----
  if (tid < MT) {
#pragma clang fp contract(off)   // numpy does separate mul then add; no FMA here
    const int m = tid;

    // x row (bit-exact staged copy)
    float xm[DDIM];
    for (int d = 0; d < DDIM; ++d) xm[d] = xlds[d * MT + m];

    // S_m = np.sum(x*x, axis=1): pairwise-8, n=64 (no tail)
    float r[8];
    for (int j = 0; j < 8; ++j) r[j] = xm[j] * xm[j];
    for (int i = 8; i < DDIM; i += 8)
      for (int j = 0; j < 8; ++j) r[j] += xm[i + j] * xm[i + j];
    const float S = ((r[0] + r[1]) + (r[2] + r[3])) + ((r[4] + r[5]) + (r[6] + r[7]));

    float bestD = FLT_MAX;
    int   besti = 0x7fffffff;
    for (int w = 0; w < 4; ++w) {
      for (int h = 0; h < 2; ++h) {
        const int idx = h ? ri2[w][m] : ri1[w][m];
        const float* crow = cb + (size_t)idx * DDIM;

        // N_k = np.sum(c*c, axis=1): same pairwise-8 pattern
        float rn[8];
        for (int j = 0; j < 8; ++j) rn[j] = crow[j] * crow[j];
        for (int i = 8; i < DDIM; i += 8)
          for (int j = 0; j < 8; ++j) rn[j] += crow[i + j] * crow[i + j];
        const float Nk =
            ((rn[0] + rn[1]) + (rn[2] + rn[3])) + ((rn[4] + rn[5]) + (rn[6] + rn[7]));

        // p ~= sgemm's fp32 dot, via correctly-rounded fp64
        double p64 = 0.0;
        for (int d = 0; d < DDIM; ++d) p64 += (double)xm[d] * (double)crow[d];
        const float pf = (float)p64;

        // d2 = (S - 2*p) + N, exactly numpy's binary-op order in fp32
        const float twop = 2.0f * pf;       // exact
        const float t1   = S - twop;        // fl32
        const float Dv   = t1 + Nk;         // fl32

        if (Dv < bestD || (Dv == bestD && idx < besti)) { bestD = Dv; besti = idx; }
      }
    }
    widx[m] = besti;
  }
  __syncthreads();

  // ---- gather winners and write z_q (coalesced stores; rows are L1/L2-hot) ----
  {
    const int w = widx[lane];
    const float* crow = cb + (size_t)w * DDIM;
    float* obase = out + (size_t)bb * (DDIM * 4096) + hw0;
#pragma unroll
    for (int p = 0; p < 16; ++p) {
      const int d = p * 4 + wv;
      obase[(size_t)d * 4096 + lane] = crow[d];
    }
  }
}

extern "C" void kernel_launch(void* const* d_in, const int* in_sizes, int n_in,
                              void* d_out, int out_size, void* d_ws, size_t ws_size,
                              hipStream_t stream) {
  const float* ze = (const float*)d_in[0];   // [8,64,64,64]
  const float* cb = (const float*)d_in[1];   // [8192,64]
  float* halfcn   = (float*)d_ws;            // 8192 floats scratch
  float* out      = (float*)d_out;           // [8,64,64,64]

  cnorm_kernel<<<KCODES / 256, 256, 0, stream>>>(cb, halfcn);
  vq_kernel<<<NTOK / MT, 256, 0, stream>>>(ze, cb, halfcn, out);
}

// Round 4
// 813.306 us; speedup vs baseline: 1.9381x; 1.9381x over previous
//
#include <hip/hip_runtime.h>
#include <float.h>

// Problem constants (fixed by reference: B=8, D=64, H=64, W=64, K=8192)
constexpr int KCODES = 8192;
constexpr int DDIM   = 64;
constexpr int NTOK   = 32768;       // B*H*W
constexpr int MT     = 64;          // tokens per WG (lane = token)
constexpr int KC     = 64;          // codes per staged LDS chunk
constexpr int NCH    = KCODES / KC; // 128 chunks
constexpr int NW     = 8;           // waves per WG (512 threads)
constexpr int CPW    = KC / NW;     // 8 codes per wave per chunk

// ---- half-codebook-norm precompute: halfcn[k] = 0.5*||c_k||^2 (phase-1 only) ----
__global__ __launch_bounds__(256) void cnorm_kernel(
    const float* __restrict__ cb, float* __restrict__ halfcn) {
  int k = blockIdx.x * 256 + threadIdx.x;
  if (k >= KCODES) return;
  const float4* row = reinterpret_cast<const float4*>(cb + (size_t)k * DDIM);
  float s = 0.f;
#pragma unroll
  for (int q = 0; q < DDIM / 4; ++q) {
    float4 v = row[q];
    s += v.x * v.x + v.y * v.y + v.z * v.z + v.w * v.w;
  }
  halfcn[k] = 0.5f * s;
}

// Phase 1: fp32 candidate generation, codebook double-buffered in LDS
//   (async global_load_lds staging; compute reads are conflict-free
//   broadcasts). lane = token, x row in 64 VGPRs, 8 waves split each chunk.
// Phase 2: numpy-fp32-faithful re-evaluation of candidates (unchanged from
//   the passing round-3 kernel): D = fl32(fl32(S - 2p) + N), pairwise-8 sums,
//   p = correctly-rounded fp32 of fp64 dot, tie -> lowest index.
__global__ __launch_bounds__(512, 4) void vq_kernel(
    const float* __restrict__ ze, const float* __restrict__ cb,
    const float* __restrict__ halfcn, float* __restrict__ out) {
  __shared__ __align__(16) float xlds[DDIM * MT];     // 16 KB  [d][m]
  __shared__ __align__(16) float clds[2][KC * DDIM];  // 2x16 KB [code][d] row-major
  __shared__ float hlds[2][KC];                       // staged 0.5*||c||^2
  __shared__ float rs1[NW][MT];  __shared__ int ri1[NW][MT];
  __shared__ float rs2[NW][MT];  __shared__ int ri2[NW][MT];
  __shared__ int   widx[MT];

  const int tid  = threadIdx.x;
  const int lane = tid & 63;          // token within tile
  const int wv   = tid >> 6;          // wave id 0..7
  const int t0   = blockIdx.x * MT;
  const int bb   = t0 >> 12;          // batch (tile never crosses batch)
  const int hw0  = t0 & 4095;
  const float* zbase = ze + (size_t)bb * (DDIM * 4096) + hw0;

  // ---- stage x tile: xlds[d*64 + m] = z_e[b, d, hw0+m] (coalesced) ----
#pragma unroll
  for (int p = 0; p < 8; ++p) {
    const int d = p * NW + wv;
    xlds[d * MT + lane] = zbase[(size_t)d * 4096 + lane];
  }

  // ---- async staging: chunk ck -> clds[buf]/hlds[buf] ----
  // Layout is contiguous row-major, matching global_load_lds's
  // wave-uniform-base + lane*16 write pattern. Wave wv stages 2 KB.
  auto stage_chunk = [&](int buf, int ck) {
    const float* gsrc = cb + (size_t)ck * KC * DDIM;  // 16 KB contiguous
#pragma unroll
    for (int i = 0; i < 2; ++i) {
      const int off = wv * 512 + i * 256;             // floats
      __builtin_amdgcn_global_load_lds(
          (const __attribute__((address_space(1))) void*)(gsrc + off + lane * 4),
          (__attribute__((address_space(3))) void*)(&clds[buf][off]), 16, 0, 0);
    }
    if (wv == 0) {
      __builtin_amdgcn_global_load_lds(
          (const __attribute__((address_space(1))) void*)(halfcn + ck * KC + lane),
          (__attribute__((address_space(3))) void*)(&hlds[buf][0]), 4, 0, 0);
    }
  };

  stage_chunk(0, 0);
  __syncthreads();  // drains staging vmcnt + xlds writes

  // ---- own token's x row into registers ----
  float xr[DDIM];
#pragma unroll
  for (int d = 0; d < DDIM; ++d) xr[d] = xlds[d * MT + lane];

  float s1 = FLT_MAX, s2 = FLT_MAX;
  int   i1 = 0, i2 = 0;

  for (int ck = 0; ck < NCH; ++ck) {
    const int cur = ck & 1;
    if (ck + 1 < NCH) stage_chunk(cur ^ 1, ck + 1);  // overlap with compute

    const float* crow0 = &clds[cur][wv * CPW * DDIM];
    const int kbase = ck * KC + wv * CPW;
#pragma unroll
    for (int j = 0; j < CPW; ++j) {
      const float4* c4 = reinterpret_cast<const float4*>(crow0 + j * DDIM);
      float a0 = 0.f, a1 = 0.f, a2 = 0.f, a3 = 0.f;   // 4 chains for ILP
#pragma unroll
      for (int q = 0; q < DDIM / 4; ++q) {
        const float4 cv = c4[q];                      // broadcast LDS read
        a0 += xr[4 * q + 0] * cv.x;
        a1 += xr[4 * q + 1] * cv.y;
        a2 += xr[4 * q + 2] * cv.z;
        a3 += xr[4 * q + 3] * cv.w;
      }
      const float s = hlds[cur][wv * CPW + j] - ((a0 + a1) + (a2 + a3));
      if (s < s1)      { s2 = s1; i2 = i1; s1 = s; i1 = kbase + j; }
      else if (s < s2) { s2 = s;  i2 = kbase + j; }
    }
    __syncthreads();  // next chunk staged (vmcnt drained) + clds reads done
  }

  rs1[wv][lane] = s1; ri1[wv][lane] = i1;
  rs2[wv][lane] = s2; ri2[wv][lane] = i2;
  __syncthreads();

  // ---- phase 2: numpy-faithful fp32 decision over the 16 candidates ----
  if (tid < MT) {
#pragma clang fp contract(off)   // numpy does separate mul then add; no FMA here
    const int m = tid;

    float xm[DDIM];
    for (int d = 0; d < DDIM; ++d) xm[d] = xlds[d * MT + m];

    // S_m = np.sum(x*x): pairwise-8, n=64
    float r[8];
    for (int j = 0; j < 8; ++j) r[j] = xm[j] * xm[j];
    for (int i = 8; i < DDIM; i += 8)
      for (int j = 0; j < 8; ++j) r[j] += xm[i + j] * xm[i + j];
    const float S = ((r[0] + r[1]) + (r[2] + r[3])) + ((r[4] + r[5]) + (r[6] + r[7]));

    float smin = rs1[0][m];
    for (int w = 1; w < NW; ++w) smin = fminf(smin, rs1[w][m]);
    const float lim = smin + 1e-4f;  // phase-1 abs error << 1e-5; winner always passes

    float bestD = FLT_MAX;
    int   besti = 0x7fffffff;
    for (int w = 0; w < NW; ++w) {
      for (int h = 0; h < 2; ++h) {
        const float sph = h ? rs2[w][m] : rs1[w][m];
        if (sph > lim) continue;
        const int idx = h ? ri2[w][m] : ri1[w][m];
        const float* crow = cb + (size_t)idx * DDIM;

        // N_k = np.sum(c*c): same pairwise-8 pattern
        float rn[8];
        for (int j = 0; j < 8; ++j) rn[j] = crow[j] * crow[j];
        for (int i = 8; i < DDIM; i += 8)
          for (int j = 0; j < 8; ++j) rn[j] += crow[i + j] * crow[i + j];
        const float Nk =
            ((rn[0] + rn[1]) + (rn[2] + rn[3])) + ((rn[4] + rn[5]) + (rn[6] + rn[7]));

        // p ~= sgemm's fp32 dot, via correctly-rounded fp64
        double p64 = 0.0;
        for (int d = 0; d < DDIM; ++d) p64 += (double)xm[d] * (double)crow[d];
        const float pf = (float)p64;

        // d2 = (S - 2*p) + N, exactly numpy's binary-op order in fp32
        const float twop = 2.0f * pf;
        const float t1   = S - twop;
        const float Dv   = t1 + Nk;

        if (Dv < bestD || (Dv == bestD && idx < besti)) { bestD = Dv; besti = idx; }
      }
    }
    widx[m] = besti;
  }
  __syncthreads();

  // ---- gather winners and write z_q (coalesced stores; rows are L2-hot) ----
  {
    const int w = widx[lane];
    const float* crow = cb + (size_t)w * DDIM;
    float* obase = out + (size_t)bb * (DDIM * 4096) + hw0;
#pragma unroll
    for (int p = 0; p < 8; ++p) {
      const int d = p * NW + wv;
      obase[(size_t)d * 4096 + lane] = crow[d];
    }
  }
}

extern "C" void kernel_launch(void* const* d_in, const int* in_sizes, int n_in,
                              void* d_out, int out_size, void* d_ws, size_t ws_size,
                              hipStream_t stream) {
  const float* ze = (const float*)d_in[0];   // [8,64,64,64]
  const float* cb = (const float*)d_in[1];   // [8192,64]
  float* halfcn   = (float*)d_ws;            // 8192 floats scratch
  float* out      = (float*)d_out;           // [8,64,64,64]

  cnorm_kernel<<<KCODES / 256, 256, 0, stream>>>(cb, halfcn);
  vq_kernel<<<NTOK / MT, 512, 0, stream>>>(ze, cb, halfcn, out);
}

// Round 5
// 243.548 us; speedup vs baseline: 6.4722x; 3.3394x over previous
//
#include <hip/hip_runtime.h>
#include <float.h>

// Problem constants (fixed by reference: B=8, D=64, H=64, W=64, K=8192)
constexpr int KCODES = 8192;
constexpr int DDIM   = 64;
constexpr int NTOK   = 32768;
constexpr int MT     = 128;              // tokens per WG (8 waves x 16)
constexpr int KC     = 64;               // codes per staged chunk
constexpr int NCH    = KCODES / KC;      // 128 chunks
constexpr int CBCHUNK = KC * DDIM * 2 * 2; // 16384 B: 64 codes x 64 d x bf16 x {hi,lo}
constexpr int HNCHUNK = KC * 4;          // 256 B of fp32 half-norms
constexpr int BUFB    = CBCHUNK + HNCHUNK; // 16640

typedef short v8s __attribute__((ext_vector_type(8)));
typedef float v4f __attribute__((ext_vector_type(4)));

static __device__ __forceinline__ unsigned short f2bf(float f) {
  union { float f; unsigned u; } v; v.f = f;
  return (unsigned short)((v.u + 0x7fffu + ((v.u >> 16) & 1u)) >> 16);  // RNE
}
static __device__ __forceinline__ float bf2f(unsigned short b) {
  union { unsigned u; float f; } v; v.u = (unsigned)b << 16;
  return v.f;
}

// ---- hn[k] = 0.5*||c_k||^2 (phase-1 C-init; only needs ~1e-5 accuracy) ----
__global__ __launch_bounds__(256) void hn_kernel(
    const float* __restrict__ cb, float* __restrict__ hn) {
  int k = blockIdx.x * 256 + threadIdx.x;
  const float4* row = reinterpret_cast<const float4*>(cb + (size_t)k * DDIM);
  float s = 0.f;
#pragma unroll
  for (int q = 0; q < DDIM / 4; ++q) {
    float4 v = row[q];
    s += v.x * v.x + v.y * v.y + v.z * v.z + v.w * v.w;
  }
  hn[k] = 0.5f * s;
}

// ---- split codebook into bf16 hi/lo, laid out FRAGMENT-LINEAR for
// mfma_f32_16x16x32_bf16 A-operand: A[m=lane&15][k=(lane>>4)*8+j].
// ws layout per 64-code chunk c: [group g:0..3][term hi/lo][kstep s:0..1][lane][j]
// => byte offset c*16384 + g*4096 + term*2048 + s*1024 + lane*16 + j*2.
__global__ __launch_bounds__(256) void split_kernel(
    const float* __restrict__ cb, unsigned short* __restrict__ wcb) {
  const int c = blockIdx.x;                 // chunk 0..127
  const int tid = threadIdx.x;
  const int g = tid >> 6, lane = tid & 63;
  const int quad = lane >> 4;
  const int code = c * KC + g * 16 + (lane & 15);
  const float* src = cb + (size_t)code * DDIM;
#pragma unroll
  for (int s = 0; s < 2; ++s) {
    v8s hi, lo;
#pragma unroll
    for (int j = 0; j < 8; ++j) {
      const float x = src[s * 32 + quad * 8 + j];
      const unsigned short h = f2bf(x);
      const unsigned short l = f2bf(x - bf2f(h));   // residual split (Sterbenz-exact sub)
      hi[j] = (short)h; lo[j] = (short)l;
    }
    const size_t b0 = ((size_t)c * CBCHUNK + g * 4096 + s * 1024 + lane * 16) / 2;
    *reinterpret_cast<v8s*>(wcb + b0)          = hi;   // term hi at +0
    *reinterpret_cast<v8s*>(wcb + b0 + 1024)   = lo;   // term lo at +2048 B
  }
}

// Phase 1: bf16-split MFMA scores acc = hn - (xh*ch + xh*cl + xl*ch)
//   (|error| < ~5e-6), per-lane top-2 over each lane-quadrant's code set.
// Phase 2: numpy-fp32-faithful decision over the 8 surfaced candidates per
//   token (unchanged passing semantics: pairwise-8 sums, D=fl(fl(S-2p)+N),
//   p = correctly-rounded fp64 dot, tie -> lowest index).
__global__ __launch_bounds__(512, 2) void vq_kernel(
    const float* __restrict__ ze, const float* __restrict__ cb,
    const float* __restrict__ hn, const unsigned short* __restrict__ wcb,
    float* __restrict__ out) {
  __shared__ __align__(16) char pool[2 * BUFB];   // 33280 B; reused post-loop

  const int tid = threadIdx.x, lane = tid & 63, wv = tid >> 6;
  const int col = lane & 15, quad = lane >> 4;
  const int t0 = blockIdx.x * MT;
  const int bb = t0 >> 12, hw0 = t0 & 4095;       // 4096 % 128 == 0: one batch per WG
  const float* zb = ze + (size_t)bb * (DDIM * 4096) + hw0;

  // ---- B-frags: tokens of this wave's tile, negated + bf16-split in regs.
  // B[k=(lane>>4)*8+j][n=lane&15]; token = wv*16 + col; d = s*32 + quad*8 + j.
  v8s nxh[2], nxl[2];
  {
    const int mtok = wv * 16 + col;
#pragma unroll
    for (int s = 0; s < 2; ++s) {
#pragma unroll
      for (int j = 0; j < 8; ++j) {
        const int d = s * 32 + quad * 8 + j;
        const float x = -zb[(size_t)d * 4096 + mtok];
        const unsigned short h = f2bf(x);
        const unsigned short l = f2bf(x - bf2f(h));
        nxh[s][j] = (short)h; nxl[s][j] = (short)l;
      }
    }
  }

  // ---- async chunk staging: frag-linear cb (16 KB) + hn (256 B) ----
  auto stage = [&](int buf, int ck) {
    char* dst = pool + buf * BUFB;
    const char* src = (const char*)wcb + (size_t)ck * CBCHUNK;
#pragma unroll
    for (int i = 0; i < 2; ++i) {
      const int off = (wv * 2 + i) * 1024;
      __builtin_amdgcn_global_load_lds(
          (const __attribute__((address_space(1))) void*)(src + off + lane * 16),
          (__attribute__((address_space(3))) void*)(dst + off), 16, 0, 0);
    }
    if (wv == 0) {
      __builtin_amdgcn_global_load_lds(
          (const __attribute__((address_space(1))) void*)(hn + ck * KC + lane),
          (__attribute__((address_space(3))) void*)(dst + CBCHUNK), 4, 0, 0);
    }
  };

  stage(0, 0);
  __syncthreads();

  float s1 = FLT_MAX, s2 = FLT_MAX;
  int   i1 = 0, i2 = 0;

  for (int ck = 0; ck < NCH; ++ck) {
    const int cur = ck & 1;
    if (ck + 1 < NCH) stage(cur ^ 1, ck + 1);
    const char* bp = pool + cur * BUFB;
#pragma unroll
    for (int g = 0; g < 4; ++g) {
      const char* fb = bp + g * 4096 + lane * 16;       // conflict-free b128
      const v8s ch0 = *reinterpret_cast<const v8s*>(fb);
      const v8s ch1 = *reinterpret_cast<const v8s*>(fb + 1024);
      const v8s cl0 = *reinterpret_cast<const v8s*>(fb + 2048);
      const v8s cl1 = *reinterpret_cast<const v8s*>(fb + 3072);
      v4f acc = *reinterpret_cast<const v4f*>(bp + CBCHUNK + g * 64 + quad * 16);
      acc = __builtin_amdgcn_mfma_f32_16x16x32_bf16(ch0, nxh[0], acc, 0, 0, 0);
      acc = __builtin_amdgcn_mfma_f32_16x16x32_bf16(ch1, nxh[1], acc, 0, 0, 0);
      acc = __builtin_amdgcn_mfma_f32_16x16x32_bf16(cl0, nxh[0], acc, 0, 0, 0);
      acc = __builtin_amdgcn_mfma_f32_16x16x32_bf16(cl1, nxh[1], acc, 0, 0, 0);
      acc = __builtin_amdgcn_mfma_f32_16x16x32_bf16(ch0, nxl[0], acc, 0, 0, 0);
      acc = __builtin_amdgcn_mfma_f32_16x16x32_bf16(ch1, nxl[1], acc, 0, 0, 0);
      // D row = code-in-16 = quad*4 + reg; col = token = lane&15
      const int kb = ck * KC + g * 16 + quad * 4;
#pragma unroll
      for (int r = 0; r < 4; ++r) {
        const float s = acc[r]; const int k = kb + r;
        if (s < s1)      { s2 = s1; i2 = i1; s1 = s; i1 = k; }
        else if (s < s2) { s2 = s;  i2 = k; }
      }
    }
    __syncthreads();   // buf reads done + next chunk's staging drained
  }

  // ---- pool reuse: per-lane partials, indexed by tid (= w*64 + quad*16 + col) ----
  float* rs1 = (float*)pool;         // [512]
  float* rs2 = rs1 + 512;
  int*   ri1 = (int*)(rs2 + 512);
  int*   ri2 = ri1 + 512;
  int*   widx = ri2 + 512;           // [128]
  rs1[tid] = s1; rs2[tid] = s2; ri1[tid] = i1; ri2[tid] = i2;
  __syncthreads();

  // ---- phase 2: numpy-faithful fp32 decision over 8 candidates/token ----
  if (tid < MT) {
#pragma clang fp contract(off)   // numpy: separate mul then add; no FMA
    const int m = tid, w = m >> 4, cc = m & 15;
    const int tok = t0 + m, b2 = tok >> 12, hw = tok & 4095;
    const float* xz = ze + (size_t)b2 * (DDIM * 4096) + hw;
    float xm[DDIM];
    for (int d = 0; d < DDIM; ++d) xm[d] = xz[(size_t)d * 4096];

    // S = np.sum(x*x): pairwise-8, n=64
    float r[8];
    for (int j = 0; j < 8; ++j) r[j] = xm[j] * xm[j];
    for (int i = 8; i < DDIM; i += 8)
      for (int j = 0; j < 8; ++j) r[j] += xm[i + j] * xm[i + j];
    const float S = ((r[0] + r[1]) + (r[2] + r[3])) + ((r[4] + r[5]) + (r[6] + r[7]));

    float smin = FLT_MAX;
    for (int q = 0; q < 4; ++q) smin = fminf(smin, rs1[w * 64 + q * 16 + cc]);
    const float lim = smin + 1e-4f;   // phase-1 err < 5e-6; numpy-winner within ~2.5e-5

    float bestD = FLT_MAX;
    int   besti = 0x7fffffff;
    for (int q = 0; q < 4; ++q) {
      for (int h = 0; h < 2; ++h) {
        const int ent = w * 64 + q * 16 + cc;
        const float sp = h ? rs2[ent] : rs1[ent];
        if (sp > lim) continue;
        const int idx = h ? ri2[ent] : ri1[ent];
        const float* crow = cb + (size_t)idx * DDIM;

        float rn[8];
        for (int j = 0; j < 8; ++j) rn[j] = crow[j] * crow[j];
        for (int i = 8; i < DDIM; i += 8)
          for (int j = 0; j < 8; ++j) rn[j] += crow[i + j] * crow[i + j];
        const float Nk =
            ((rn[0] + rn[1]) + (rn[2] + rn[3])) + ((rn[4] + rn[5]) + (rn[6] + rn[7]));

        double p64 = 0.0;
        for (int d = 0; d < DDIM; ++d) p64 += (double)xm[d] * (double)crow[d];
        const float pf = (float)p64;

        const float twop = 2.0f * pf;
        const float t1   = S - twop;
        const float Dv   = t1 + Nk;
        if (Dv < bestD || (Dv == bestD && idx < besti)) { bestD = Dv; besti = idx; }
      }
    }
    widx[m] = besti;
  }
  __syncthreads();

  // ---- gather winners, write z_q (coalesced stores; cb rows L2-hot) ----
  {
    const int m = tid & 127, dg = tid >> 7;    // dg 0..3
    const int wi = widx[m];
    const float* crow = cb + (size_t)wi * DDIM;
    float* ob = out + (size_t)bb * (DDIM * 4096) + hw0;
#pragma unroll
    for (int p = 0; p < 16; ++p) {
      const int d = dg * 16 + p;
      ob[(size_t)d * 4096 + m] = crow[d];
    }
  }
}

extern "C" void kernel_launch(void* const* d_in, const int* in_sizes, int n_in,
                              void* d_out, int out_size, void* d_ws, size_t ws_size,
                              hipStream_t stream) {
  const float* ze = (const float*)d_in[0];    // [8,64,64,64]
  const float* cb = (const float*)d_in[1];    // [8192,64]
  float* hn = (float*)d_ws;                                    // 32 KB
  unsigned short* wcb = (unsigned short*)((char*)d_ws + 32768); // 2 MB frag-linear split
  float* out = (float*)d_out;

  hn_kernel<<<KCODES / 256, 256, 0, stream>>>(cb, hn);
  split_kernel<<<NCH, 256, 0, stream>>>(cb, wcb);
  vq_kernel<<<NTOK / MT, 512, 0, stream>>>(ze, cb, hn, wcb, out);
}

// Round 6
// 204.310 us; speedup vs baseline: 7.7152x; 1.1921x over previous
//
#include <hip/hip_runtime.h>
#include <float.h>

// Problem constants (fixed by reference: B=8, D=64, H=64, W=64, K=8192)
constexpr int KCODES = 8192;
constexpr int DDIM   = 64;
constexpr int NTOK   = 32768;
constexpr int MT     = 128;                // tokens per WG (2 token-groups x 64)
constexpr int KC     = 64;                 // codes per staged chunk
constexpr int NCH    = KCODES / KC;        // 128 chunks
constexpr int NITER  = NCH / 2;            // 64: each wave scans one k-half
constexpr int CBCHUNK = KC * DDIM * 2 * 2; // 16384 B (64 codes x 64 d x bf16 x {hi,lo})
constexpr int HNCHUNK = KC * 4;            // 256 B fp32 biased half-norms
constexpr int BUFB    = CBCHUNK + HNCHUNK; // 16640

typedef short v8s __attribute__((ext_vector_type(8)));
typedef float v4f __attribute__((ext_vector_type(4)));

#define AS1 __attribute__((address_space(1)))
#define AS3 __attribute__((address_space(3)))

static __device__ __forceinline__ unsigned short f2bf(float f) {
  union { float f; unsigned u; } v; v.f = f;
  return (unsigned short)((v.u + 0x7fffu + ((v.u >> 16) & 1u)) >> 16);  // RNE
}
static __device__ __forceinline__ float bf2f(unsigned short b) {
  union { unsigned u; float f; } v; v.u = (unsigned)b << 16;
  return v.f;
}

// ---- hn[k] = 0.5*||c_k||^2 + 2.0 (bias keeps phase-1 scores positive so
// their fp32 bit patterns are monotone for the packed-key argmin) ----
__global__ __launch_bounds__(256) void hn_kernel(
    const float* __restrict__ cb, float* __restrict__ hn) {
  int k = blockIdx.x * 256 + threadIdx.x;
  const float4* row = reinterpret_cast<const float4*>(cb + (size_t)k * DDIM);
  float s = 0.f;
#pragma unroll
  for (int q = 0; q < DDIM / 4; ++q) {
    float4 v = row[q];
    s += v.x * v.x + v.y * v.y + v.z * v.z + v.w * v.w;
  }
  hn[k] = 0.5f * s + 2.0f;
}

// ---- split codebook into bf16 hi/lo, FRAGMENT-LINEAR for
// mfma_f32_16x16x32_bf16 A-operand: A[m=lane&15][k=(lane>>4)*8+j].
// Per 64-code chunk c: byte off = c*16384 + g*4096 + term*2048 + s*1024 + lane*16 + j*2.
__global__ __launch_bounds__(256) void split_kernel(
    const float* __restrict__ cb, unsigned short* __restrict__ wcb) {
  const int c = blockIdx.x;                 // chunk 0..127
  const int tid = threadIdx.x;
  const int g = tid >> 6, lane = tid & 63;
  const int quad = lane >> 4;
  const int code = c * KC + g * 16 + (lane & 15);
  const float* src = cb + (size_t)code * DDIM;
#pragma unroll
  for (int s = 0; s < 2; ++s) {
    v8s hi, lo;
#pragma unroll
    for (int j = 0; j < 8; ++j) {
      const float x = src[s * 32 + quad * 8 + j];
      const unsigned short h = f2bf(x);
      const unsigned short l = f2bf(x - bf2f(h));   // residual (Sterbenz-exact sub)
      hi[j] = (short)h; lo[j] = (short)l;
    }
    const size_t b0 = ((size_t)c * CBCHUNK + g * 4096 + s * 1024 + lane * 16) / 2;
    *reinterpret_cast<v8s*>(wcb + b0)        = hi;
    *reinterpret_cast<v8s*>(wcb + b0 + 1024) = lo;
  }
}

// Phase 1: bf16-split MFMA, wave holds 64 tokens (4 B-sets) in VGPRs so each
//   staged code-frag ds_read feeds 4 MFMAs (LDS traffic /4 vs round 5).
//   In-WG split-K: 4 waves = 2 token-groups x 2 codebook-halves. Packed-key
//   (score-bits | 3-bit local idx) per-half-chunk argmin: 1 and_or + 1 min_u32
//   per value. Per-(lane,set) running top-2 over half-chunk winners.
// Phase 2: numpy-fp32-faithful decision over surfaced candidates (unchanged
//   passing semantics: pairwise-8 sums, D=fl(fl(S-2p)+N), p = correctly
//   rounded fp64 dot, tie -> lowest index).
__global__ __launch_bounds__(256, 1) void vq_kernel(
    const float* __restrict__ ze, const float* __restrict__ cb,
    const float* __restrict__ hn, const unsigned short* __restrict__ wcb,
    float* __restrict__ out) {
  __shared__ __align__(16) char pool[2][2][BUFB];   // [k-half stream][dbuf]; 66560 B

  const int tid = threadIdx.x, lane = tid & 63, wv = tid >> 6;
  const int col = lane & 15, quad = lane >> 4;
  const int tg = wv & 1;            // token group (0: tokens 0..63, 1: 64..127)
  const int kh = wv >> 1;           // codebook half (chunks kh*64 .. kh*64+63)
  const int t0 = blockIdx.x * MT;
  const int bb = t0 >> 12, hw0 = t0 & 4095;   // 4096 % 128 == 0: one batch per WG
  const float* zb = ze + (size_t)bb * (DDIM * 4096) + hw0;

  // ---- B-frags: 4 sets x 16 tokens, negated + bf16-split, in registers.
  // B[k=(lane>>4)*8+j][n=lane&15]; token = tg*64 + s*16 + col; d = ks*32+quad*8+j.
  v8s nxh[4][2], nxl[4][2];
#pragma unroll
  for (int s = 0; s < 4; ++s) {
    const int mtok = tg * 64 + s * 16 + col;
#pragma unroll
    for (int ks = 0; ks < 2; ++ks) {
#pragma unroll
      for (int j = 0; j < 8; ++j) {
        const int d = ks * 32 + quad * 8 + j;
        const float x = -zb[(size_t)d * 4096 + mtok];
        const unsigned short h = f2bf(x);
        const unsigned short l = f2bf(x - bf2f(h));
        nxh[s][ks][j] = (short)h; nxl[s][ks][j] = (short)l;
      }
    }
  }

  // ---- async staging: wave (tg,kh) stages half tg of chunk kh*64+it ----
  auto stage = [&](int buf, int it) {
    const int ck = kh * NITER + it;
    const char* src = (const char*)wcb + (size_t)ck * CBCHUNK + tg * 8192;
    char* dst = &pool[kh][buf][0] + tg * 8192;
#pragma unroll
    for (int i = 0; i < 8; ++i) {
      __builtin_amdgcn_global_load_lds(
          (const AS1 void*)(src + i * 1024 + lane * 16),
          (AS3 void*)(dst + i * 1024), 16, 0, 0);
    }
    if (tg == 0) {
      __builtin_amdgcn_global_load_lds(
          (const AS1 void*)(hn + ck * KC + lane),
          (AS3 void*)(&pool[kh][buf][0] + CBCHUNK), 4, 0, 0);
    }
  };

  stage(0, 0);
  __syncthreads();

  float bs1[4], bs2[4];
  int   bi1[4], bi2[4];
#pragma unroll
  for (int s = 0; s < 4; ++s) { bs1[s] = bs2[s] = FLT_MAX; bi1[s] = bi2[s] = 0; }

  for (int it = 0; it < NITER; ++it) {
    const int cur = it & 1;
    if (it + 1 < NITER) stage(cur ^ 1, it + 1);
    const char* bp = &pool[kh][cur][0];
    const int ck = kh * NITER + it;

    unsigned kmin[4][2];
#pragma unroll
    for (int s = 0; s < 4; ++s) kmin[s][0] = kmin[s][1] = 0xFFFFFFFFu;

#pragma unroll
    for (int g = 0; g < 4; ++g) {
      const char* fb = bp + g * 4096 + lane * 16;       // conflict-free b128
      const v8s ch0 = *reinterpret_cast<const v8s*>(fb);
      const v8s ch1 = *reinterpret_cast<const v8s*>(fb + 1024);
      const v8s cl0 = *reinterpret_cast<const v8s*>(fb + 2048);
      const v8s cl1 = *reinterpret_cast<const v8s*>(fb + 3072);
      const v4f hnv = *reinterpret_cast<const v4f*>(bp + CBCHUNK + g * 64 + quad * 16);

      v4f acc[4];
#pragma unroll
      for (int s = 0; s < 4; ++s) acc[s] = hnv;
      // 4 independent chains interleaved -> MFMA latency hidden at 1 wave/SIMD
#pragma unroll
      for (int s = 0; s < 4; ++s)
        acc[s] = __builtin_amdgcn_mfma_f32_16x16x32_bf16(ch0, nxh[s][0], acc[s], 0, 0, 0);
#pragma unroll
      for (int s = 0; s < 4; ++s)
        acc[s] = __builtin_amdgcn_mfma_f32_16x16x32_bf16(ch1, nxh[s][1], acc[s], 0, 0, 0);
#pragma unroll
      for (int s = 0; s < 4; ++s)
        acc[s] = __builtin_amdgcn_mfma_f32_16x16x32_bf16(cl0, nxh[s][0], acc[s], 0, 0, 0);
#pragma unroll
      for (int s = 0; s < 4; ++s)
        acc[s] = __builtin_amdgcn_mfma_f32_16x16x32_bf16(cl1, nxh[s][1], acc[s], 0, 0, 0);
#pragma unroll
      for (int s = 0; s < 4; ++s)
        acc[s] = __builtin_amdgcn_mfma_f32_16x16x32_bf16(ch0, nxl[s][0], acc[s], 0, 0, 0);
#pragma unroll
      for (int s = 0; s < 4; ++s)
        acc[s] = __builtin_amdgcn_mfma_f32_16x16x32_bf16(ch1, nxl[s][1], acc[s], 0, 0, 0);

      // packed keys: (score-bits & ~7) | local; local = (g&1)*4 + r in half g>>1
      const int half = g >> 1;
#pragma unroll
      for (int s = 0; s < 4; ++s) {
#pragma unroll
        for (int r = 0; r < 4; ++r) {
          const unsigned key =
              (__float_as_uint(acc[s][r]) & ~7u) | (unsigned)((g & 1) * 4 + r);
          kmin[s][half] = min(kmin[s][half], key);
        }
      }
    }

    // decode the 2 half-chunk winners per set; update running top-2
#pragma unroll
    for (int s = 0; s < 4; ++s) {
#pragma unroll
      for (int half = 0; half < 2; ++half) {
        const unsigned km = kmin[s][half];
        const int local = km & 7;
        const float sc = __uint_as_float(km & ~7u);   // biased (+2.0) approx score
        const int g = half * 2 + (local >> 2);
        const int k = ck * KC + g * 16 + quad * 4 + (local & 3);
        if (sc < bs1[s])      { bs2[s] = bs1[s]; bi2[s] = bi1[s]; bs1[s] = sc; bi1[s] = k; }
        else if (sc < bs2[s]) { bs2[s] = sc; bi2[s] = k; }
      }
    }
    __syncthreads();   // buf reads done + next chunk staging drained
  }

  // ---- pool reuse: candidates[src 0..7][token 0..127], src = kh*4 + quad ----
  float* c_s1 = (float*)&pool[0][0][0];
  float* c_s2 = c_s1 + 1024;
  int*   c_i1 = (int*)(c_s2 + 1024);
  int*   c_i2 = c_i1 + 1024;
  int*   widx = c_i2 + 1024;
  {
    const int src = kh * 4 + quad;
#pragma unroll
    for (int s = 0; s < 4; ++s) {
      const int m = tg * 64 + s * 16 + col;
      c_s1[src * MT + m] = bs1[s];  c_i1[src * MT + m] = bi1[s];
      c_s2[src * MT + m] = bs2[s];  c_i2[src * MT + m] = bi2[s];
    }
  }
  __syncthreads();

  // ---- phase 2: numpy-faithful fp32 decision over 16 candidates/token ----
  if (tid < MT) {
#pragma clang fp contract(off)   // numpy: separate mul then add; no FMA
    const int m = tid;
    const float* xz = zb + m;     // token t0+m, same batch
    float xm[DDIM];
    for (int d = 0; d < DDIM; ++d) xm[d] = xz[(size_t)d * 4096];

    // S = np.sum(x*x): pairwise-8, n=64
    float r[8];
    for (int j = 0; j < 8; ++j) r[j] = xm[j] * xm[j];
    for (int i = 8; i < DDIM; i += 8)
      for (int j = 0; j < 8; ++j) r[j] += xm[i + j] * xm[i + j];
    const float S = ((r[0] + r[1]) + (r[2] + r[3])) + ((r[4] + r[5]) + (r[6] + r[7]));

    float smin = FLT_MAX;
    for (int src = 0; src < 8; ++src) smin = fminf(smin, c_s1[src * MT + m]);
    const float lim = smin + 1e-4f;  // phase-1 err < ~7e-6 incl. key quantization

    float bestD = FLT_MAX;
    int   besti = 0x7fffffff;
    for (int src = 0; src < 8; ++src) {
      for (int h = 0; h < 2; ++h) {
        const float sp = h ? c_s2[src * MT + m] : c_s1[src * MT + m];
        if (sp > lim) continue;
        const int idx = h ? c_i2[src * MT + m] : c_i1[src * MT + m];
        const float* crow = cb + (size_t)idx * DDIM;

        float rn[8];
        for (int j = 0; j < 8; ++j) rn[j] = crow[j] * crow[j];
        for (int i = 8; i < DDIM; i += 8)
          for (int j = 0; j < 8; ++j) rn[j] += crow[i + j] * crow[i + j];
        const float Nk =
            ((rn[0] + rn[1]) + (rn[2] + rn[3])) + ((rn[4] + rn[5]) + (rn[6] + rn[7]));

        double p64 = 0.0;
        for (int d = 0; d < DDIM; ++d) p64 += (double)xm[d] * (double)crow[d];
        const float pf = (float)p64;

        const float twop = 2.0f * pf;
        const float t1   = S - twop;
        const float Dv   = t1 + Nk;
        if (Dv < bestD || (Dv == bestD && idx < besti)) { bestD = Dv; besti = idx; }
      }
    }
    widx[m] = besti;
  }
  __syncthreads();

  // ---- gather winners, write z_q (coalesced stores; cb rows L2-hot) ----
  {
    const int m = tid & 127, dg = tid >> 7;    // dg 0..1
    const int wi = widx[m];
    const float* crow = cb + (size_t)wi * DDIM;
    float* ob = out + (size_t)bb * (DDIM * 4096) + hw0;
#pragma unroll
    for (int p = 0; p < 32; ++p) {
      const int d = dg * 32 + p;
      ob[(size_t)d * 4096 + m] = crow[d];
    }
  }
}

extern "C" void kernel_launch(void* const* d_in, const int* in_sizes, int n_in,
                              void* d_out, int out_size, void* d_ws, size_t ws_size,
                              hipStream_t stream) {
  const float* ze = (const float*)d_in[0];    // [8,64,64,64]
  const float* cb = (const float*)d_in[1];    // [8192,64]
  float* hn = (float*)d_ws;                                     // 32 KB
  unsigned short* wcb = (unsigned short*)((char*)d_ws + 32768); // 2 MB frag-linear split
  float* out = (float*)d_out;

  hn_kernel<<<KCODES / 256, 256, 0, stream>>>(cb, hn);
  split_kernel<<<NCH, 256, 0, stream>>>(cb, wcb);
  vq_kernel<<<NTOK / MT, 256, 0, stream>>>(ze, cb, hn, wcb, out);
}

// Round 7
// 173.705 us; speedup vs baseline: 9.0745x; 1.1762x over previous
//
#include <hip/hip_runtime.h>
#include <float.h>

// Problem constants (fixed by reference: B=8, D=64, H=64, W=64, K=8192)
constexpr int KCODES = 8192;
constexpr int DDIM   = 64;
constexpr int NTOK   = 32768;
constexpr int MT     = 64;                 // tokens per WG (4 sets x 16, all 4 waves)
constexpr int KC     = 64;                 // codes per staged chunk
constexpr int NCH    = KCODES / KC;        // 128 chunks
constexpr int CBCHUNK = KC * DDIM * 2 * 2; // 16384 B (64 codes x 64 d x bf16 x {hi,lo})

typedef short v8s __attribute__((ext_vector_type(8)));
typedef float v4f __attribute__((ext_vector_type(4)));

#define AS1 __attribute__((address_space(1)))
#define AS3 __attribute__((address_space(3)))

static __device__ __forceinline__ unsigned short f2bf(float f) {
  union { float f; unsigned u; } v; v.f = f;
  return (unsigned short)((v.u + 0x7fffu + ((v.u >> 16) & 1u)) >> 16);  // RNE
}
static __device__ __forceinline__ float bf2f(unsigned short b) {
  union { unsigned u; float f; } v; v.u = (unsigned)b << 16;
  return v.f;
}

// ---- fused prep: bf16 hi/lo split (FRAGMENT-LINEAR for mfma_16x16x32_bf16
// A-operand: A[m=lane&15][k=(lane>>4)*8+j]) + biased half-norms
// hn[k] = 0.5*||c_k||^2 + 2.0 (bias keeps phase-1 scores positive -> fp32
// bit pattern monotone for the packed-key argmin).
// Per 64-code chunk c: byte off = c*16384 + g*4096 + term*2048 + ks*1024 + lane*16 + j*2.
__global__ __launch_bounds__(256) void prep_kernel(
    const float* __restrict__ cb, unsigned short* __restrict__ wcb,
    float* __restrict__ hn) {
  const int c = blockIdx.x;                 // chunk 0..127
  const int tid = threadIdx.x;
  const int g = tid >> 6, lane = tid & 63;
  const int quad = lane >> 4, col = lane & 15;
  const int code = c * KC + g * 16 + col;
  const float* src = cb + (size_t)code * DDIM;
  float sq = 0.f;
#pragma unroll
  for (int ks = 0; ks < 2; ++ks) {
    v8s hi, lo;
#pragma unroll
    for (int j = 0; j < 8; ++j) {
      const float x = src[ks * 32 + quad * 8 + j];
      sq += x * x;
      const unsigned short h = f2bf(x);
      const unsigned short l = f2bf(x - bf2f(h));   // residual (Sterbenz-exact sub)
      hi[j] = (short)h; lo[j] = (short)l;
    }
    const size_t b0 = ((size_t)c * CBCHUNK + g * 4096 + ks * 1024 + lane * 16) / 2;
    *reinterpret_cast<v8s*>(wcb + b0)        = hi;
    *reinterpret_cast<v8s*>(wcb + b0 + 1024) = lo;
  }
  // cross-quad reduction: lanes quad*16+col for quad 0..3 hold this code's dims
  sq += __shfl_xor(sq, 16);
  sq += __shfl_xor(sq, 32);
  if (quad == 0) hn[code] = 0.5f * sq + 2.0f;
}

// Phase 1: bf16-split MFMA scores acc = hn - (xh*ch + xh*cl + xl*ch)
//   (|err| < ~5e-6). Wave wv owns code-group g=wv of every chunk; 64 tokens
//   (4 B-sets) resident in VGPRs. Grid 512 -> 2 WGs/CU: barrier drains and
//   MFMA latency overlap across co-resident WGs (m114 co-scheduling).
// Phase 2: numpy-fp32-faithful decision over 32 surfaced candidates/token
//   (16 cells x top-2), split 4-ways across waves + LDS merge. Semantics
//   unchanged from the passing rounds: pairwise-8 sums, D=fl(fl(S-2p)+N),
//   p = correctly-rounded fp64 dot, tie -> lowest index.
__global__ __launch_bounds__(256, 2) void vq_kernel(
    const float* __restrict__ ze, const float* __restrict__ cb,
    const float* __restrict__ hn, const unsigned short* __restrict__ wcb,
    float* __restrict__ out) {
  __shared__ __align__(16) char pool[2 * CBCHUNK];   // 32 KB double buffer; reused

  const int tid = threadIdx.x, lane = tid & 63, wv = tid >> 6;
  const int col = lane & 15, quad = lane >> 4;
  const int t0 = blockIdx.x * MT;
  const int bb = t0 >> 12, hw0 = t0 & 4095;   // 4096 % 64 == 0: one batch per WG
  const float* zb = ze + (size_t)bb * (DDIM * 4096) + hw0;

  // ---- B-frags: 4 sets x 16 tokens, negated + bf16-split, in registers.
  // B[k=(lane>>4)*8+j][n=lane&15]; token = s*16 + col; d = ks*32 + quad*8 + j.
  v8s nxh[4][2], nxl[4][2];
#pragma unroll
  for (int s = 0; s < 4; ++s) {
    const int mtok = s * 16 + col;
#pragma unroll
    for (int ks = 0; ks < 2; ++ks) {
#pragma unroll
      for (int j = 0; j < 8; ++j) {
        const int d = ks * 32 + quad * 8 + j;
        const float x = -zb[(size_t)d * 4096 + mtok];
        const unsigned short h = f2bf(x);
        const unsigned short l = f2bf(x - bf2f(h));
        nxh[s][ks][j] = (short)h; nxl[s][ks][j] = (short)l;
      }
    }
  }

  // ---- async staging: wave wv stages only the 4 KB it will consume ----
  auto stage = [&](int buf, int ck) {
    const char* src = (const char*)wcb + (size_t)ck * CBCHUNK + wv * 4096;
    char* dst = pool + buf * CBCHUNK + wv * 4096;
#pragma unroll
    for (int i = 0; i < 4; ++i) {
      __builtin_amdgcn_global_load_lds(
          (const AS1 void*)(src + i * 1024 + lane * 16),
          (AS3 void*)(dst + i * 1024), 16, 0, 0);
    }
  };

  // hn: register double-buffer prefetch (L2-hot broadcast loads, no LDS)
  const float* hnp = hn + wv * 16 + quad * 4;
  v4f hnv_cur = *reinterpret_cast<const v4f*>(hnp);   // it = 0
  v4f hnv_next = hnv_cur;

  stage(0, 0);
  __syncthreads();

  float bs1[4], bs2[4];
  int   bi1[4], bi2[4];
#pragma unroll
  for (int s = 0; s < 4; ++s) { bs1[s] = bs2[s] = FLT_MAX; bi1[s] = bi2[s] = 0; }

  for (int it = 0; it < NCH; ++it) {
    const int cur = it & 1;
    if (it + 1 < NCH) {
      stage(cur ^ 1, it + 1);
      hnv_next = *reinterpret_cast<const v4f*>(hnp + (it + 1) * KC);
    }

    const char* fb = pool + cur * CBCHUNK + wv * 4096 + lane * 16;  // conflict-free b128
    const v8s ch0 = *reinterpret_cast<const v8s*>(fb);
    const v8s ch1 = *reinterpret_cast<const v8s*>(fb + 1024);
    const v8s cl0 = *reinterpret_cast<const v8s*>(fb + 2048);
    const v8s cl1 = *reinterpret_cast<const v8s*>(fb + 3072);

    v4f acc[4];
#pragma unroll
    for (int s = 0; s < 4; ++s) acc[s] = hnv_cur;
    // 4 independent chains interleaved (6-deep each)
#pragma unroll
    for (int s = 0; s < 4; ++s)
      acc[s] = __builtin_amdgcn_mfma_f32_16x16x32_bf16(ch0, nxh[s][0], acc[s], 0, 0, 0);
#pragma unroll
    for (int s = 0; s < 4; ++s)
      acc[s] = __builtin_amdgcn_mfma_f32_16x16x32_bf16(ch1, nxh[s][1], acc[s], 0, 0, 0);
#pragma unroll
    for (int s = 0; s < 4; ++s)
      acc[s] = __builtin_amdgcn_mfma_f32_16x16x32_bf16(cl0, nxh[s][0], acc[s], 0, 0, 0);
#pragma unroll
    for (int s = 0; s < 4; ++s)
      acc[s] = __builtin_amdgcn_mfma_f32_16x16x32_bf16(cl1, nxh[s][1], acc[s], 0, 0, 0);
#pragma unroll
    for (int s = 0; s < 4; ++s)
      acc[s] = __builtin_amdgcn_mfma_f32_16x16x32_bf16(ch0, nxl[s][0], acc[s], 0, 0, 0);
#pragma unroll
    for (int s = 0; s < 4; ++s)
      acc[s] = __builtin_amdgcn_mfma_f32_16x16x32_bf16(ch1, nxl[s][1], acc[s], 0, 0, 0);

    // packed-key argmin over the 4 scores per set (2-bit local index),
    // then running top-2 update per (lane, set) cell
#pragma unroll
    for (int s = 0; s < 4; ++s) {
      unsigned km = 0xFFFFFFFFu;
#pragma unroll
      for (int r = 0; r < 4; ++r)
        km = min(km, (__float_as_uint(acc[s][r]) & ~3u) | (unsigned)r);
      const float sc = __uint_as_float(km & ~3u);   // biased (+2.0) approx score
      const int k = it * KC + wv * 16 + quad * 4 + (int)(km & 3u);
      if (sc < bs1[s])      { bs2[s] = bs1[s]; bi2[s] = bi1[s]; bs1[s] = sc; bi1[s] = k; }
      else if (sc < bs2[s]) { bs2[s] = sc; bi2[s] = k; }
    }
    __syncthreads();   // own-buf reads done + next chunk's staging drained
    hnv_cur = hnv_next;
  }

  // ---- pool reuse: candidates[src 0..15][token 0..63], src = wv*4 + quad ----
  float* c_s1 = (float*)pool;          // 4 KB
  float* c_s2 = c_s1 + 1024;           // 4 KB
  int*   c_i1 = (int*)(c_s2 + 1024);   // 4 KB
  int*   c_i2 = c_i1 + 1024;           // 4 KB
  float* pD   = (float*)(c_i2 + 1024); // [4][64] 1 KB
  int*   pI   = (int*)(pD + 256);      // [4][64] 1 KB
  int*   widx = pI + 256;              // [64]
  {
    const int srcid = wv * 4 + quad;
#pragma unroll
    for (int s = 0; s < 4; ++s) {
      const int m = s * 16 + col;
      c_s1[srcid * MT + m] = bs1[s];  c_i1[srcid * MT + m] = bi1[s];
      c_s2[srcid * MT + m] = bs2[s];  c_i2[srcid * MT + m] = bi2[s];
    }
  }
  __syncthreads();

  // ---- phase 2: numpy-faithful fp32 decision, 4-way split across waves ----
  {
#pragma clang fp contract(off)   // numpy: separate mul then add; no FMA
    const int m = lane;          // token
    const float* xz = zb + m;
    float xm[DDIM];
    for (int d = 0; d < DDIM; ++d) xm[d] = xz[(size_t)d * 4096];

    // S = np.sum(x*x): pairwise-8, n=64
    float r[8];
    for (int j = 0; j < 8; ++j) r[j] = xm[j] * xm[j];
    for (int i = 8; i < DDIM; i += 8)
      for (int j = 0; j < 8; ++j) r[j] += xm[i + j] * xm[i + j];
    const float S = ((r[0] + r[1]) + (r[2] + r[3])) + ((r[4] + r[5]) + (r[6] + r[7]));

    float smin = FLT_MAX;
    for (int src = 0; src < 16; ++src) smin = fminf(smin, c_s1[src * MT + m]);
    const float lim = smin + 1e-4f;  // phase-1 err < ~7e-6 incl. key quantization

    float bestD = FLT_MAX;
    int   besti = 0x7fffffff;
    for (int src = wv * 4; src < wv * 4 + 4; ++src) {
      for (int h = 0; h < 2; ++h) {
        const float sp = h ? c_s2[src * MT + m] : c_s1[src * MT + m];
        if (sp > lim) continue;
        const int idx = h ? c_i2[src * MT + m] : c_i1[src * MT + m];
        const float* crow = cb + (size_t)idx * DDIM;

        float rn[8];
        for (int j = 0; j < 8; ++j) rn[j] = crow[j] * crow[j];
        for (int i = 8; i < DDIM; i += 8)
          for (int j = 0; j < 8; ++j) rn[j] += crow[i + j] * crow[i + j];
        const float Nk =
            ((rn[0] + rn[1]) + (rn[2] + rn[3])) + ((rn[4] + rn[5]) + (rn[6] + rn[7]));

        double p64 = 0.0;
        for (int d = 0; d < DDIM; ++d) p64 += (double)xm[d] * (double)crow[d];
        const float pf = (float)p64;

        const float twop = 2.0f * pf;
        const float t1   = S - twop;
        const float Dv   = t1 + Nk;
        if (Dv < bestD || (Dv == bestD && idx < besti)) { bestD = Dv; besti = idx; }
      }
    }
    pD[wv * MT + m] = bestD;
    pI[wv * MT + m] = besti;
  }
  __syncthreads();

  if (tid < MT) {
    const int m = tid;
    float bD = pD[m]; int bI = pI[m];
    for (int w = 1; w < 4; ++w) {
      const float d2 = pD[w * MT + m]; const int i2 = pI[w * MT + m];
      if (d2 < bD || (d2 == bD && i2 < bI)) { bD = d2; bI = i2; }
    }
    widx[m] = bI;
  }
  __syncthreads();

  // ---- gather winners, write z_q (coalesced 64-float rows; cb L2-hot) ----
  {
    const int wi = widx[lane];
    const float* crow = cb + (size_t)wi * DDIM;
    float* ob = out + (size_t)bb * (DDIM * 4096) + hw0;
#pragma unroll
    for (int p = 0; p < 16; ++p) {
      const int d = wv * 16 + p;
      ob[(size_t)d * 4096 + lane] = crow[d];
    }
  }
}

extern "C" void kernel_launch(void* const* d_in, const int* in_sizes, int n_in,
                              void* d_out, int out_size, void* d_ws, size_t ws_size,
                              hipStream_t stream) {
  const float* ze = (const float*)d_in[0];    // [8,64,64,64]
  const float* cb = (const float*)d_in[1];    // [8192,64]
  float* hn = (float*)d_ws;                                     // 32 KB
  unsigned short* wcb = (unsigned short*)((char*)d_ws + 32768); // 2 MB frag-linear split
  float* out = (float*)d_out;

  prep_kernel<<<NCH, 256, 0, stream>>>(cb, wcb, hn);
  vq_kernel<<<NTOK / MT, 256, 0, stream>>>(ze, cb, hn, wcb, out);
}